// Round 11
// baseline (964.963 us; speedup 1.0000x reference)
//
#include <hip/hip_runtime.h>
#include <hip/hip_bf16.h>
#include <stdint.h>

#define V_ 32000
#define D_ 512
#define H_ 8
#define L_ 6
#define S_ 1024
#define B_ 4
#define DH_ 64
#define M_ (B_*S_)   // 4096

typedef __attribute__((ext_vector_type(8))) short bf16x8;
typedef __attribute__((ext_vector_type(4))) short short4b;
typedef __attribute__((ext_vector_type(4))) float f32x4;

__device__ __forceinline__ short f2bs(float f) {
  union { float f; uint32_t u; } x; x.f = f;
  uint32_t r = (x.u + 0x7FFFu + ((x.u >> 16) & 1u)) >> 16;
  return (short)r;
}
__device__ __forceinline__ float bs2f(short s) {
  union { uint32_t u; float f; } x; x.u = ((uint32_t)(uint16_t)s) << 16;
  return x.f;
}

__device__ __forceinline__ f32x4 mfma16(bf16x8 a, bf16x8 b, f32x4 c) {
  return __builtin_amdgcn_mfma_f32_16x16x32_bf16(a, b, c, 0, 0, 0);
}

// async global->LDS, 16B per lane; LDS dest = wave-uniform base + lane*16
__device__ __forceinline__ void gload16(const short* g, char* lds) {
  __builtin_amdgcn_global_load_lds(
      (const __attribute__((address_space(1))) uint32_t*)g,
      (__attribute__((address_space(3))) uint32_t*)lds, 16, 0, 0);
}

template<int N> __device__ __forceinline__ void waitvm() {
  if constexpr (N == 0) asm volatile("s_waitcnt vmcnt(0)" ::: "memory");
  else if constexpr (N == 3) asm volatile("s_waitcnt vmcnt(3)" ::: "memory");
  else if constexpr (N == 4) asm volatile("s_waitcnt vmcnt(4)" ::: "memory");
  else if constexpr (N == 6) asm volatile("s_waitcnt vmcnt(6)" ::: "memory");
  else if constexpr (N == 8) asm volatile("s_waitcnt vmcnt(8)" ::: "memory");
}

// ---- transpose + fp32->bf16 convert: out[(orow0+n)*K + k] = in[k*N+n] ----
__global__ __launch_bounds__(256) void transpose_cvt(const float* __restrict__ in,
    short* __restrict__ out, int K, int N, size_t in_slab, size_t out_slab, int orow0) {
  __shared__ float tile[32][33];
  const float* inp = in + (size_t)blockIdx.z * in_slab;
  short* outp = out + (size_t)blockIdx.z * out_slab;
  int kb = blockIdx.y * 32, nb = blockIdx.x * 32;
  int tx = threadIdx.x, ty = threadIdx.y;   // block (32,8)
  for (int r = ty; r < 32; r += 8) {
    int k = kb + r, n = nb + tx;
    tile[r][tx] = (k < K && n < N) ? inp[(size_t)k * N + n] : 0.f;
  }
  __syncthreads();
  for (int r = ty; r < 32; r += 8) {
    int n = nb + r, k = kb + tx;
    if (n < N && k < K) outp[(size_t)(orow0 + n) * K + k] = f2bs(tile[tx][r]);
  }
}

__global__ __launch_bounds__(256) void pack_qkv_bias(const float* __restrict__ bq,
    const float* __restrict__ bk, const float* __restrict__ bv, float* __restrict__ o) {
  int i = blockIdx.x * 256 + threadIdx.x;   // < L_*1536
  int l = i / 1536, c = i - l * 1536;
  float v = (c < 512) ? bq[l * 512 + c] : (c < 1024) ? bk[l * 512 + c - 512]
                                                     : bv[l * 512 + c - 1024];
  o[i] = v;
}

// ---- embedding ----
__global__ __launch_bounds__(256) void embed_k(const int* __restrict__ ids,
    const float* __restrict__ tok, const float* __restrict__ pos, float* __restrict__ h) {
  int bs = blockIdx.x;
  int tid = threadIdx.x;
  int s = bs & (S_ - 1);
  int id = ids[bs];
  float2 te = *(const float2*)(tok + (size_t)id * D_ + tid * 2);
  float2 pe = *(const float2*)(pos + (size_t)s * D_ + tid * 2);
  float2 r; r.x = te.x + pe.x; r.y = te.y + pe.y;
  *(float2*)(h + (size_t)bs * D_ + tid * 2) = r;
}

// ---- LayerNorm, one wave per row, 4 rows/block, no LDS ----
__global__ __launch_bounds__(256) void ln4_k(const float* __restrict__ in,
    const float* __restrict__ w, const float* __restrict__ bb, short* __restrict__ outb) {
  int wv = threadIdx.x >> 6, lane = threadIdx.x & 63;
  int row = blockIdx.x * 4 + wv;
  const float* x = in + (size_t)row * D_ + lane * 8;
  float4 v0 = *(const float4*)x;
  float4 v1 = *(const float4*)(x + 4);
  float s = v0.x + v0.y + v0.z + v0.w + v1.x + v1.y + v1.z + v1.w;
  #pragma unroll
  for (int o = 32; o; o >>= 1) s += __shfl_xor(s, o);
  float mu = s * (1.f / D_);
  float d[8] = {v0.x-mu, v0.y-mu, v0.z-mu, v0.w-mu, v1.x-mu, v1.y-mu, v1.z-mu, v1.w-mu};
  float s2 = 0.f;
  #pragma unroll
  for (int j = 0; j < 8; ++j) s2 += d[j] * d[j];
  #pragma unroll
  for (int o = 32; o; o >>= 1) s2 += __shfl_xor(s2, o);
  float rs = rsqrtf(s2 * (1.f / D_) + 1e-5f);
  float4 w0 = *(const float4*)(w + lane * 8);
  float4 w1 = *(const float4*)(w + lane * 8 + 4);
  float4 b0 = *(const float4*)(bb + lane * 8);
  float4 b1 = *(const float4*)(bb + lane * 8 + 4);
  float wj[8] = {w0.x,w0.y,w0.z,w0.w,w1.x,w1.y,w1.z,w1.w};
  float bj[8] = {b0.x,b0.y,b0.z,b0.w,b1.x,b1.y,b1.z,b1.w};
  short o8[8];
  #pragma unroll
  for (int j = 0; j < 8; ++j) o8[j] = f2bs(d[j] * rs * wj[j] + bj[j]);
  *(uint4*)(outb + (size_t)row * D_ + lane * 8) = *(uint4*)o8;
}

// ========== BMxBN MFMA GEMM, BK=64, dbuf + counted vmcnt (round-10 verified) =====
template<int AMODE, int EMODE, int BM, int BN>
__global__ __launch_bounds__(256) void gemm3_k(
    const short* __restrict__ A, const short* __restrict__ Wt,
    const float* __restrict__ bias, float* __restrict__ Cf,
    short* __restrict__ Cb, const short* __restrict__ Agg,
    float* __restrict__ Hf, const short* __restrict__ zpad,
    int M, int N, int K)
{
  constexpr int NF = BN / 32;             // B frags per wave
  constexpr int AR = BM / 32;             // A staging rounds (32 rows each)
  constexpr int BR = BN / 32;             // B staging rounds
  constexpr int MI = BM / 32;             // A frags per wave
  constexpr int LOADS = AR + BR;          // gloads per wave per stage
  __shared__ __align__(16) char As[2][BM * 128];
  __shared__ __align__(16) char Bs[2][BN * 128];
  const int tid = threadIdx.x;
  const int lane = tid & 63, w = tid >> 6;
  const int m0 = blockIdx.x * BM, n0 = blockIdx.y * BN;
  const int l15 = lane & 15, l4 = lane >> 4;
  const int wm = (w >> 1) * (BM / 2), wn = (w & 1) * (BN / 2);

  const int lrow_b = tid >> 3;            // 0..31
  const int kel0 = (tid & 7) * 8;
  const short* agp[AR];
  const short* agpHi[AR];
  #pragma unroll
  for (int r = 0; r < AR; ++r) {
    int lrow = r * 32 + lrow_b;
    int row = m0 + lrow;
    int kel = kel0 ^ ((lrow & 7) << 3);
    if (AMODE == 0) {
      agp[r] = A + (size_t)row * K + kel;
    } else if (AMODE == 1) {
      agp[r]   = A + (size_t)row * D_ + kel;
      agpHi[r] = ((row & (S_ - 1)) == (S_ - 1)) ? zpad + kel
                                                : A + (size_t)(row + 1) * D_ + kel;
    } else {
      agp[r] = ((row & (S_ - 1)) == 0) ? zpad + kel : A + (size_t)(row - 1) * D_ + kel;
    }
  }
  const short* bgp[BR];
  #pragma unroll
  for (int r = 0; r < BR; ++r) {
    int lrow = r * 32 + lrow_b;
    int kel = kel0 ^ ((lrow & 7) << 3);
    bgp[r] = Wt + (size_t)(n0 + lrow) * K + kel;
  }

  auto stage = [&](int buf, int k0) {
    #pragma unroll
    for (int r = 0; r < AR; ++r) {
      const short* gp;
      if (AMODE == 1) gp = (k0 < D_) ? agp[r] + k0 : agpHi[r] + (k0 - D_);
      else gp = agp[r] + k0;
      gload16(gp, As[buf] + r * 4096 + w * 1024);
    }
    #pragma unroll
    for (int r = 0; r < BR; ++r)
      gload16(bgp[r] + k0, Bs[buf] + r * 4096 + w * 1024);
  };

  const int rswz = (l15 & 7) << 4;
  int aoff[MI], boff[NF];
  #pragma unroll
  for (int i = 0; i < MI; ++i) aoff[i] = (wm + i * 16 + l15) * 128;
  #pragma unroll
  for (int j = 0; j < NF; ++j) boff[j] = (wn + j * 16 + l15) * 128;

  f32x4 acc[MI][NF] = {};

  const int nk = K >> 6;
  stage(0, 0);
  for (int t = 0; t < nk; ++t) {
    const int cur = t & 1;
    if (t + 1 < nk) { stage(cur ^ 1, (t + 1) * 64); waitvm<LOADS>(); }
    else waitvm<0>();
    __syncthreads();
    #pragma unroll
    for (int kk = 0; kk < 2; ++kk) {
      const int cb = (kk * 64 + l4 * 16) ^ rswz;
      bf16x8 af[MI], bfr[NF];
      #pragma unroll
      for (int i = 0; i < MI; ++i) af[i] = *(const bf16x8*)(As[cur] + aoff[i] + cb);
      #pragma unroll
      for (int j = 0; j < NF; ++j) bfr[j] = *(const bf16x8*)(Bs[cur] + boff[j] + cb);
      __builtin_amdgcn_s_setprio(1);
      #pragma unroll
      for (int i = 0; i < MI; ++i)
        #pragma unroll
        for (int j = 0; j < NF; ++j)
          acc[i][j] = mfma16(af[i], bfr[j], acc[i][j]);
      __builtin_amdgcn_s_setprio(0);
    }
    __syncthreads();
  }

  const int rowb = m0 + wm + l4 * 4;
  const int colb = n0 + wn + l15;
  #pragma unroll
  for (int i = 0; i < MI; ++i) {
    #pragma unroll
    for (int j = 0; j < NF; ++j) {
      int col = colb + j * 16;
      float bias_v = bias ? bias[col] : 0.f;
      #pragma unroll
      for (int r = 0; r < 4; ++r) {
        int row = rowb + i * 16 + r;
        size_t idx = (size_t)row * N + col;
        float v = acc[i][j][r] + bias_v;
        if (EMODE == 0) {
          if (Cb) { Cf[idx] = v; Cb[idx] = f2bs(v); }
          else __builtin_nontemporal_store(v, &Cf[idx]);
        } else if (EMODE == 1) {
          Cf[idx] += v;
        } else if (EMODE == 2) {
          Cb[idx] = f2bs(fmaxf(v, 0.f));
        } else if (EMODE == 3) {
          float g = 1.f / (1.f + __expf(-v));
          float aggv = ((row & (S_ - 1)) == 0) ? 0.f : bs2f(Agg[idx - N]);
          float tn = Cf[idx] + g * aggv;
          Cf[idx] = tn; Cb[idx] = f2bs(tn);
        } else if (EMODE == 5) {
          float g = 1.f / (1.f + __expf(-v));
          float aggv = ((row & (S_ - 1)) == 0) ? 0.f : bs2f(Agg[idx - N]);
          Hf[idx] += Cf[idx] + g * aggv;
        } else {   // 4: QKV packed bf16; q cols scaled into exp2 domain
          float sc = (col < D_) ? 0.180336880f : 1.f;   // 0.125 * log2(e)
          Cb[idx] = f2bs(v * sc);
        }
      }
    }
  }
}

// ========== 128x128 head GEMM: XCD swizzle, counted vmcnt, COALESCED epilogue ====
__global__ __launch_bounds__(256) void gemm2_k(
    const short* __restrict__ A, const short* __restrict__ Wt,
    float* __restrict__ Cf, int M, int N, int K)
{
  __shared__ __align__(16) char smem[65536];   // As[2][16K] | Bs[2][16K]; reused as Lf
  char* Asb = smem;
  char* Bsb = smem + 32768;
  const int tid = threadIdx.x;
  const int lane = tid & 63, w = tid >> 6;
  // XCD-bijective swizzle (nwg % 8 == 0)
  const int nwg = gridDim.x * gridDim.y;
  const int bid = blockIdx.x + blockIdx.y * gridDim.x;
  const int swz = (bid & 7) * (nwg >> 3) + (bid >> 3);
  const int m0 = (swz % gridDim.x) * 128, n0 = (swz / gridDim.x) * 128;
  const int l15 = lane & 15, l4 = lane >> 4;
  const int wm = (w >> 1) * 64, wn = (w & 1) * 64;

  const int lrow_b = tid >> 3;
  const int kel0 = (tid & 7) * 8;
  const short* agp[4];
  const short* bgp[4];
  #pragma unroll
  for (int r = 0; r < 4; ++r) {
    int lrow = r * 32 + lrow_b;
    int kel = kel0 ^ ((lrow & 7) << 3);
    agp[r] = A + (size_t)(m0 + lrow) * K + kel;
    bgp[r] = Wt + (size_t)(n0 + lrow) * K + kel;
  }
  auto stage = [&](int buf, int k0) {
    #pragma unroll
    for (int r = 0; r < 4; ++r) gload16(agp[r] + k0, Asb + buf * 16384 + r * 4096 + w * 1024);
    #pragma unroll
    for (int r = 0; r < 4; ++r) gload16(bgp[r] + k0, Bsb + buf * 16384 + r * 4096 + w * 1024);
  };

  const int rswz = (l15 & 7) << 4;
  int aoff[4], boff[4];
  #pragma unroll
  for (int i = 0; i < 4; ++i) aoff[i] = (wm + i * 16 + l15) * 128;
  #pragma unroll
  for (int j = 0; j < 4; ++j) boff[j] = (wn + j * 16 + l15) * 128;

  f32x4 acc[4][4] = {};
  const int nk = K >> 6;
  stage(0, 0);
  for (int t = 0; t < nk; ++t) {
    const int cur = t & 1;
    if (t + 1 < nk) { stage(cur ^ 1, (t + 1) * 64); waitvm<8>(); }
    else waitvm<0>();
    __syncthreads();
    #pragma unroll
    for (int kk = 0; kk < 2; ++kk) {
      const int cb = (kk * 64 + l4 * 16) ^ rswz;
      bf16x8 af[4], bfr[4];
      #pragma unroll
      for (int i = 0; i < 4; ++i)
        af[i] = *(const bf16x8*)(Asb + cur * 16384 + aoff[i] + cb);
      #pragma unroll
      for (int j = 0; j < 4; ++j)
        bfr[j] = *(const bf16x8*)(Bsb + cur * 16384 + boff[j] + cb);
      __builtin_amdgcn_s_setprio(1);
      #pragma unroll
      for (int i = 0; i < 4; ++i)
        #pragma unroll
        for (int j = 0; j < 4; ++j)
          acc[i][j] = mfma16(af[i], bfr[j], acc[i][j]);
      __builtin_amdgcn_s_setprio(0);
    }
    __syncthreads();   // last iter: all LDS reads done block-wide after this
  }

  // ---- coalesced epilogue: acc -> swizzled LDS (fp32) -> dwordx4 stores ----
  float* Lf = (float*)smem;        // 128x128 fp32 = 64 KB
  #pragma unroll
  for (int i = 0; i < 4; ++i)
    #pragma unroll
    for (int j = 0; j < 4; ++j)
      #pragma unroll
      for (int r = 0; r < 4; ++r) {
        int row = wm + i * 16 + l4 * 4 + r;
        int c = wn + j * 16 + l15;
        int cs = c ^ ((((row & 7) ^ ((c >> 5) & 3))) << 2);
        Lf[row * 128 + cs] = acc[i][j][r];
      }
  __syncthreads();
  #pragma unroll
  for (int s = 0; s < 16; ++s) {
    int row = (tid >> 5) + s * 8;
    int cb = (tid & 31) * 4;
    int cs = cb ^ ((((row & 7) ^ ((cb >> 5) & 3))) << 2);
    f32x4 v = *(const f32x4*)&Lf[row * 128 + cs];
    __builtin_nontemporal_store(v, (f32x4*)&Cf[(size_t)(m0 + row) * N + n0 + cb]);
  }
}

// ---- flash attention, swapped QK^T (round-7 verified): softmax lane-local;
//      P^T via per-wave LDS; PV with Vt[64][72] XOR-swizzled layout. ----
__global__ __launch_bounds__(256) void fattn_k(const short* __restrict__ Qkv,
    short* __restrict__ avb)
{
  __shared__ short Ks[64][72];        // [key][dh]
  __shared__ short Vt[64][72];        // [dh][key ^ swz]
  __shared__ short Pt[4][16][72];     // per-wave P^T as [q][key]
  const int QS = 3 * D_;
  const int tid = threadIdx.x, lane = tid & 63, w = tid >> 6;
  const int bx = blockIdx.x;
  const int qt = 15 - (bx >> 5);      // heavy tiles first
  const int bh = bx & 31, b = bh >> 3, hh = bh & 7;
  const int l15 = lane & 15, g = lane >> 4;

  const int qrow = qt * 64 + w * 16 + l15;   // this lane's q
  const short* qptr = Qkv + (size_t)(b * S_ + qrow) * QS + hh * DH_;
  bf16x8 qa0 = *(const bf16x8*)(qptr + g * 8);
  bf16x8 qa1 = *(const bf16x8*)(qptr + 32 + g * 8);

  f32x4 o[4] = {};        // o[nt][r] = O[qrow][d = nt*16 + g*4 + r]
  float mx = -1e30f, lsum = 0.f;

  auto gptr = [&](int kt, int i) {
    int c = tid + i * 256;
    int key = c >> 3, d0 = (c & 7) * 8;
    return Qkv + (size_t)(b * S_ + kt * 64 + key) * QS + hh * DH_ + d0;
  };
  uint4 kvA[2], vvA[2], kvB[2], vvB[2];
  auto load_t = [&](int kt, uint4 kv[2], uint4 vv[2]) {
    #pragma unroll
    for (int i = 0; i < 2; ++i) {
      const short* base = gptr(kt, i);
      kv[i] = *(const uint4*)(base + D_);
      vv[i] = *(const uint4*)(base + 2 * D_);
    }
  };
  auto store_t = [&](uint4 kv[2], uint4 vv[2]) {
    #pragma unroll
    for (int i = 0; i < 2; ++i) {
      int c = tid + i * 256;
      int key = c >> 3, d0 = (c & 7) * 8;
      *(uint4*)&Ks[key][d0] = kv[i];
      short vs[8]; *(uint4*)vs = vv[i];
      int a = (c & 7);
      #pragma unroll
      for (int j = 0; j < 8; ++j)
        Vt[d0 + j][key ^ (a << 3)] = vs[j];
    }
  };

  auto compute = [&](int kt) {
    const int key0 = kt * 64;
    f32x4 sc[4] = {};
    __builtin_amdgcn_s_setprio(1);
    #pragma unroll
    for (int f = 0; f < 4; ++f) {
      bf16x8 ka0 = *(const bf16x8*)&Ks[f * 16 + l15][g * 8];
      bf16x8 ka1 = *(const bf16x8*)&Ks[f * 16 + l15][32 + g * 8];
      sc[f] = mfma16(ka0, qa0, sc[f]);
      sc[f] = mfma16(ka1, qa1, sc[f]);
    }
    __builtin_amdgcn_s_setprio(0);

    float s[16];
    #pragma unroll
    for (int f = 0; f < 4; ++f)
      #pragma unroll
      for (int r = 0; r < 4; ++r)
        s[f * 4 + r] = sc[f][r];
    if (kt == qt) {
      #pragma unroll
      for (int f = 0; f < 4; ++f)
        #pragma unroll
        for (int r = 0; r < 4; ++r)
          if (key0 + f * 16 + g * 4 + r > qrow) s[f * 4 + r] = -1e30f;
    }
    float cm = s[0];
    #pragma unroll
    for (int i = 1; i < 16; ++i) cm = fmaxf(cm, s[i]);
    cm = fmaxf(cm, __shfl_xor(cm, 16));
    cm = fmaxf(cm, __shfl_xor(cm, 32));
    float mn = fmaxf(mx, cm);
    float fr = exp2f(mx - mn);
    mx = mn;
    float p[16], ss = 0.f;
    #pragma unroll
    for (int i = 0; i < 16; ++i) { p[i] = exp2f(s[i] - mn); ss += p[i]; }
    ss += __shfl_xor(ss, 16);
    ss += __shfl_xor(ss, 32);
    lsum = lsum * fr + ss;
    #pragma unroll
    for (int nt = 0; nt < 4; ++nt)
      #pragma unroll
      for (int r = 0; r < 4; ++r) o[nt][r] *= fr;

    #pragma unroll
    for (int f = 0; f < 4; ++f) {
      short tmp[4];
      #pragma unroll
      for (int r = 0; r < 4; ++r) tmp[r] = f2bs(p[f * 4 + r]);
      *(uint2*)&Pt[w][l15][f * 16 + g * 4] = *(uint2*)tmp;
    }
    __builtin_amdgcn_sched_barrier(0);
    bf16x8 pb0 = *(const bf16x8*)&Pt[w][l15][g * 8];
    bf16x8 pb1 = *(const bf16x8*)&Pt[w][l15][32 + g * 8];

    __builtin_amdgcn_s_setprio(1);
    #pragma unroll
    for (int nt = 0; nt < 4; ++nt) {
      int dim = nt * 16 + l15;
      int vswz = ((dim >> 3) & 7) << 3;
      bf16x8 va0 = *(const bf16x8*)&Vt[dim][(g * 8) ^ vswz];
      bf16x8 va1 = *(const bf16x8*)&Vt[dim][(32 + g * 8) ^ vswz];
      o[nt] = mfma16(va0, pb0, o[nt]);
      o[nt] = mfma16(va1, pb1, o[nt]);
    }
    __builtin_amdgcn_s_setprio(0);
  };

  const int ntiles = qt + 1;
  load_t(0, kvA, vvA);
  int kt = 0;
  while (true) {
    __syncthreads();
    store_t(kvA, vvA);
    if (kt + 1 < ntiles) load_t(kt + 1, kvB, vvB);
    __syncthreads();
    compute(kt);
    ++kt; if (kt >= ntiles) break;
    __syncthreads();
    store_t(kvB, vvB);
    if (kt + 1 < ntiles) load_t(kt + 1, kvA, vvA);
    __syncthreads();
    compute(kt);
    ++kt; if (kt >= ntiles) break;
  }

  const float inv = 1.f / lsum;
  #pragma unroll
  for (int nt = 0; nt < 4; ++nt) {
    short ov[4];
    #pragma unroll
    for (int r = 0; r < 4; ++r) ov[r] = f2bs(o[nt][r] * inv);
    *(short4b*)(avb + (size_t)(b * S_ + qrow) * D_ + hh * DH_ + nt * 16 + g * 4) =
        *(short4b*)ov;
  }
}

extern "C" void kernel_launch(void* const* d_in, const int* in_sizes, int n_in,
                              void* d_out, int out_size, void* d_ws, size_t ws_size,
                              hipStream_t stream) {
  const int*   ids   = (const int*)d_in[0];
  const float* tok   = (const float*)d_in[1];
  const float* pos   = (const float*)d_in[2];
  const float* Wq    = (const float*)d_in[3];
  const float* bq    = (const float*)d_in[4];
  const float* Wk    = (const float*)d_in[5];
  const float* bk    = (const float*)d_in[6];
  const float* Wv    = (const float*)d_in[7];
  const float* bv    = (const float*)d_in[8];
  const float* Wo    = (const float*)d_in[9];
  const float* bo    = (const float*)d_in[10];
  const float* ln1w  = (const float*)d_in[11];
  const float* ln1b  = (const float*)d_in[12];
  const float* ln2w  = (const float*)d_in[13];
  const float* ln2b  = (const float*)d_in[14];
  const float* Win   = (const float*)d_in[15];
  const float* bin   = (const float*)d_in[16];
  const float* Wedge = (const float*)d_in[17];
  const float* bedge = (const float*)d_in[18];
  const float* Wgate = (const float*)d_in[19];
  const float* bgate = (const float*)d_in[20];
  const float* lnfw  = (const float*)d_in[21];
  const float* lnfb  = (const float*)d_in[22];
  const float* Whead = (const float*)d_in[23];
  float* out = (float*)d_out;

  char* ws = (char*)d_ws;
  size_t off = 0;
  auto alloc = [&](size_t bytes) {
    void* p = ws + off;
    off = (off + bytes + 255) & ~(size_t)255;
    return p;
  };
  short* wqkv   = (short*)alloc((size_t)L_ * 3 * D_ * D_ * 2);
  float* bqkv   = (float*)alloc((size_t)L_ * 3 * D_ * 4);
  short* wto    = (short*)alloc((size_t)L_ * D_ * D_ * 2);
  short* wtin   = (short*)alloc((size_t)L_ * D_ * D_ * 2);
  short* wtgate = (short*)alloc((size_t)L_ * D_ * D_ * 2);
  short* wtedge = (short*)alloc((size_t)L_ * 2 * D_ * D_ * 2);
  short* wthead = (short*)alloc((size_t)V_ * D_ * 2);
  short* zpad   = (short*)alloc(4096);
  float* hbuf   = (float*)alloc((size_t)M_ * D_ * 4);
  short* xb     = (short*)alloc((size_t)M_ * D_ * 2);
  short* qkvb   = (short*)alloc((size_t)M_ * 3 * D_ * 2);
  short* avb    = (short*)alloc((size_t)M_ * D_ * 2);
  float* tbuf   = (float*)alloc((size_t)M_ * D_ * 4);
  short* tbf    = (short*)alloc((size_t)M_ * D_ * 2);
  short* msgb   = (short*)alloc((size_t)M_ * D_ * 2);
  (void)ws_size; (void)in_sizes; (void)n_in; (void)out_size;

  (void)hipMemsetAsync(zpad, 0, 4096, stream);

  dim3 tblk(32, 8);
  transpose_cvt<<<dim3(16, 16, L_), tblk, 0, stream>>>(Wq, wqkv, D_, D_, (size_t)D_*D_, (size_t)3*D_*D_, 0);
  transpose_cvt<<<dim3(16, 16, L_), tblk, 0, stream>>>(Wk, wqkv, D_, D_, (size_t)D_*D_, (size_t)3*D_*D_, D_);
  transpose_cvt<<<dim3(16, 16, L_), tblk, 0, stream>>>(Wv, wqkv, D_, D_, (size_t)D_*D_, (size_t)3*D_*D_, 2*D_);
  transpose_cvt<<<dim3(16, 16, L_), tblk, 0, stream>>>(Wo, wto, D_, D_, (size_t)D_*D_, (size_t)D_*D_, 0);
  transpose_cvt<<<dim3(16, 16, L_), tblk, 0, stream>>>(Win, wtin, D_, D_, (size_t)D_*D_, (size_t)D_*D_, 0);
  transpose_cvt<<<dim3(16, 16, L_), tblk, 0, stream>>>(Wgate, wtgate, D_, D_, (size_t)D_*D_, (size_t)D_*D_, 0);
  transpose_cvt<<<dim3(16, 32, L_), tblk, 0, stream>>>(Wedge, wtedge, 2*D_, D_, (size_t)2*D_*D_, (size_t)2*D_*D_, 0);
  transpose_cvt<<<dim3(V_/32, 16, 1), tblk, 0, stream>>>(Whead, wthead, D_, V_, (size_t)D_*V_, (size_t)D_*V_, 0);
  pack_qkv_bias<<<(L_ * 3 * D_) / 256, 256, 0, stream>>>(bq, bk, bv, bqkv);

  embed_k<<<M_, 256, 0, stream>>>(ids, tok, pos, hbuf);

  dim3 g32(M_ / 32, D_ / 64);         // (128,8) -> 1024 blocks = 4/CU
  dim3 gqkv(M_ / 32, 3 * D_ / 64);    // (128,24) -> 3072 blocks
  for (int l = 0; l < L_; ++l) {
    size_t wofs = (size_t)l * D_ * D_;
    ln4_k<<<M_ / 4, 256, 0, stream>>>(hbuf, ln1w + l * D_, ln1b + l * D_, xb);
    gemm3_k<0,4,32,64><<<gqkv, 256, 0, stream>>>(xb, wqkv + (size_t)l * 3 * D_ * D_,
        bqkv + (size_t)l * 3 * D_, nullptr, qkvb, nullptr, nullptr, zpad, M_, 3 * D_, D_);
    fattn_k<<<B_ * H_ * (S_ / 64), 256, 0, stream>>>(qkvb, avb);
    gemm3_k<0,1,32,64><<<g32, 256, 0, stream>>>(avb, wto + wofs, bo + l * D_,
        hbuf, nullptr, nullptr, nullptr, zpad, M_, D_, D_);
    ln4_k<<<M_ / 4, 256, 0, stream>>>(hbuf, ln2w + l * D_, ln2b + l * D_, xb);
    gemm3_k<0,0,32,64><<<g32, 256, 0, stream>>>(xb, wtin + wofs, bin + l * D_,
        tbuf, tbf, nullptr, nullptr, zpad, M_, D_, D_);
    // TreeFFN iter 0
    gemm3_k<1,2,32,64><<<g32, 256, 0, stream>>>(tbf, wtedge + (size_t)l * 2 * D_ * D_,
        bedge + l * D_, nullptr, msgb, nullptr, nullptr, zpad, M_, D_, 2 * D_);
    gemm3_k<2,3,32,64><<<g32, 256, 0, stream>>>(msgb, wtgate + wofs, bgate + l * D_,
        tbuf, tbf, msgb, nullptr, zpad, M_, D_, D_);
    // TreeFFN iter 1 + fused residual h += t
    gemm3_k<1,2,32,64><<<g32, 256, 0, stream>>>(tbf, wtedge + (size_t)l * 2 * D_ * D_,
        bedge + l * D_, nullptr, msgb, nullptr, nullptr, zpad, M_, D_, 2 * D_);
    gemm3_k<2,5,32,64><<<g32, 256, 0, stream>>>(msgb, wtgate + wofs, bgate + l * D_,
        tbuf, nullptr, msgb, hbuf, zpad, M_, D_, D_);
  }
  ln4_k<<<M_ / 4, 256, 0, stream>>>(hbuf, lnfw, lnfb, xb);
  gemm2_k<<<dim3(M_ / 128, V_ / 128), 256, 0, stream>>>(xb, wthead, out, M_, V_, D_);
}

// Round 12
// 949.380 us; speedup vs baseline: 1.0164x; 1.0164x over previous
//
#include <hip/hip_runtime.h>
#include <hip/hip_bf16.h>
#include <stdint.h>

#define V_ 32000
#define D_ 512
#define H_ 8
#define L_ 6
#define S_ 1024
#define B_ 4
#define DH_ 64
#define M_ (B_*S_)   // 4096

typedef __attribute__((ext_vector_type(8))) short bf16x8;
typedef __attribute__((ext_vector_type(4))) short short4b;
typedef __attribute__((ext_vector_type(4))) float f32x4;

__device__ __forceinline__ short f2bs(float f) {
  union { float f; uint32_t u; } x; x.f = f;
  uint32_t r = (x.u + 0x7FFFu + ((x.u >> 16) & 1u)) >> 16;
  return (short)r;
}
__device__ __forceinline__ float bs2f(short s) {
  union { uint32_t u; float f; } x; x.u = ((uint32_t)(uint16_t)s) << 16;
  return x.f;
}

__device__ __forceinline__ f32x4 mfma16(bf16x8 a, bf16x8 b, f32x4 c) {
  return __builtin_amdgcn_mfma_f32_16x16x32_bf16(a, b, c, 0, 0, 0);
}

// async global->LDS, 16B per lane; LDS dest = wave-uniform base + lane*16
__device__ __forceinline__ void gload16(const short* g, char* lds) {
  __builtin_amdgcn_global_load_lds(
      (const __attribute__((address_space(1))) uint32_t*)g,
      (__attribute__((address_space(3))) uint32_t*)lds, 16, 0, 0);
}

template<int N> __device__ __forceinline__ void waitvm() {
  if constexpr (N == 0) asm volatile("s_waitcnt vmcnt(0)" ::: "memory");
  else if constexpr (N == 3) asm volatile("s_waitcnt vmcnt(3)" ::: "memory");
  else if constexpr (N == 4) asm volatile("s_waitcnt vmcnt(4)" ::: "memory");
  else if constexpr (N == 6) asm volatile("s_waitcnt vmcnt(6)" ::: "memory");
  else if constexpr (N == 8) asm volatile("s_waitcnt vmcnt(8)" ::: "memory");
}

// ---- transpose + fp32->bf16 convert: out[(orow0+n)*K + k] = in[k*N+n] ----
__global__ __launch_bounds__(256) void transpose_cvt(const float* __restrict__ in,
    short* __restrict__ out, int K, int N, size_t in_slab, size_t out_slab, int orow0) {
  __shared__ float tile[32][33];
  const float* inp = in + (size_t)blockIdx.z * in_slab;
  short* outp = out + (size_t)blockIdx.z * out_slab;
  int kb = blockIdx.y * 32, nb = blockIdx.x * 32;
  int tx = threadIdx.x, ty = threadIdx.y;   // block (32,8)
  for (int r = ty; r < 32; r += 8) {
    int k = kb + r, n = nb + tx;
    tile[r][tx] = (k < K && n < N) ? inp[(size_t)k * N + n] : 0.f;
  }
  __syncthreads();
  for (int r = ty; r < 32; r += 8) {
    int n = nb + r, k = kb + tx;
    if (n < N && k < K) outp[(size_t)(orow0 + n) * K + k] = f2bs(tile[tx][r]);
  }
}

__global__ __launch_bounds__(256) void pack_qkv_bias(const float* __restrict__ bq,
    const float* __restrict__ bk, const float* __restrict__ bv, float* __restrict__ o) {
  int i = blockIdx.x * 256 + threadIdx.x;   // < L_*1536
  int l = i / 1536, c = i - l * 1536;
  float v = (c < 512) ? bq[l * 512 + c] : (c < 1024) ? bk[l * 512 + c - 512]
                                                     : bv[l * 512 + c - 1024];
  o[i] = v;
}

// ---- embedding ----
__global__ __launch_bounds__(256) void embed_k(const int* __restrict__ ids,
    const float* __restrict__ tok, const float* __restrict__ pos, float* __restrict__ h) {
  int bs = blockIdx.x;
  int tid = threadIdx.x;
  int s = bs & (S_ - 1);
  int id = ids[bs];
  float2 te = *(const float2*)(tok + (size_t)id * D_ + tid * 2);
  float2 pe = *(const float2*)(pos + (size_t)s * D_ + tid * 2);
  float2 r; r.x = te.x + pe.x; r.y = te.y + pe.y;
  *(float2*)(h + (size_t)bs * D_ + tid * 2) = r;
}

// ---- LayerNorm, one wave per row, 4 rows/block, no LDS ----
__global__ __launch_bounds__(256) void ln4_k(const float* __restrict__ in,
    const float* __restrict__ w, const float* __restrict__ bb, short* __restrict__ outb) {
  int wv = threadIdx.x >> 6, lane = threadIdx.x & 63;
  int row = blockIdx.x * 4 + wv;
  const float* x = in + (size_t)row * D_ + lane * 8;
  float4 v0 = *(const float4*)x;
  float4 v1 = *(const float4*)(x + 4);
  float s = v0.x + v0.y + v0.z + v0.w + v1.x + v1.y + v1.z + v1.w;
  #pragma unroll
  for (int o = 32; o; o >>= 1) s += __shfl_xor(s, o);
  float mu = s * (1.f / D_);
  float d[8] = {v0.x-mu, v0.y-mu, v0.z-mu, v0.w-mu, v1.x-mu, v1.y-mu, v1.z-mu, v1.w-mu};
  float s2 = 0.f;
  #pragma unroll
  for (int j = 0; j < 8; ++j) s2 += d[j] * d[j];
  #pragma unroll
  for (int o = 32; o; o >>= 1) s2 += __shfl_xor(s2, o);
  float rs = rsqrtf(s2 * (1.f / D_) + 1e-5f);
  float4 w0 = *(const float4*)(w + lane * 8);
  float4 w1 = *(const float4*)(w + lane * 8 + 4);
  float4 b0 = *(const float4*)(bb + lane * 8);
  float4 b1 = *(const float4*)(bb + lane * 8 + 4);
  float wj[8] = {w0.x,w0.y,w0.z,w0.w,w1.x,w1.y,w1.z,w1.w};
  float bj[8] = {b0.x,b0.y,b0.z,b0.w,b1.x,b1.y,b1.z,b1.w};
  short o8[8];
  #pragma unroll
  for (int j = 0; j < 8; ++j) o8[j] = f2bs(d[j] * rs * wj[j] + bj[j]);
  *(uint4*)(outb + (size_t)row * D_ + lane * 8) = *(uint4*)o8;
}

// ========== BMxBN MFMA GEMM, BK=64, dbuf + counted vmcnt (round-10 verified) =====
template<int AMODE, int EMODE, int BM, int BN>
__global__ __launch_bounds__(256) void gemm3_k(
    const short* __restrict__ A, const short* __restrict__ Wt,
    const float* __restrict__ bias, float* __restrict__ Cf,
    short* __restrict__ Cb, const short* __restrict__ Agg,
    float* __restrict__ Hf, const short* __restrict__ zpad,
    int M, int N, int K)
{
  constexpr int NF = BN / 32;             // B frags per wave
  constexpr int AR = BM / 32;             // A staging rounds (32 rows each)
  constexpr int BR = BN / 32;             // B staging rounds
  constexpr int MI = BM / 32;             // A frags per wave
  constexpr int LOADS = AR + BR;          // gloads per wave per stage
  __shared__ __align__(16) char As[2][BM * 128];
  __shared__ __align__(16) char Bs[2][BN * 128];
  const int tid = threadIdx.x;
  const int lane = tid & 63, w = tid >> 6;
  const int m0 = blockIdx.x * BM, n0 = blockIdx.y * BN;
  const int l15 = lane & 15, l4 = lane >> 4;
  const int wm = (w >> 1) * (BM / 2), wn = (w & 1) * (BN / 2);

  const int lrow_b = tid >> 3;            // 0..31
  const int kel0 = (tid & 7) * 8;
  const short* agp[AR];
  const short* agpHi[AR];
  #pragma unroll
  for (int r = 0; r < AR; ++r) {
    int lrow = r * 32 + lrow_b;
    int row = m0 + lrow;
    int kel = kel0 ^ ((lrow & 7) << 3);
    if (AMODE == 0) {
      agp[r] = A + (size_t)row * K + kel;
    } else if (AMODE == 1) {
      agp[r]   = A + (size_t)row * D_ + kel;
      agpHi[r] = ((row & (S_ - 1)) == (S_ - 1)) ? zpad + kel
                                                : A + (size_t)(row + 1) * D_ + kel;
    } else {
      agp[r] = ((row & (S_ - 1)) == 0) ? zpad + kel : A + (size_t)(row - 1) * D_ + kel;
    }
  }
  const short* bgp[BR];
  #pragma unroll
  for (int r = 0; r < BR; ++r) {
    int lrow = r * 32 + lrow_b;
    int kel = kel0 ^ ((lrow & 7) << 3);
    bgp[r] = Wt + (size_t)(n0 + lrow) * K + kel;
  }

  auto stage = [&](int buf, int k0) {
    #pragma unroll
    for (int r = 0; r < AR; ++r) {
      const short* gp;
      if (AMODE == 1) gp = (k0 < D_) ? agp[r] + k0 : agpHi[r] + (k0 - D_);
      else gp = agp[r] + k0;
      gload16(gp, As[buf] + r * 4096 + w * 1024);
    }
    #pragma unroll
    for (int r = 0; r < BR; ++r)
      gload16(bgp[r] + k0, Bs[buf] + r * 4096 + w * 1024);
  };

  const int rswz = (l15 & 7) << 4;
  int aoff[MI], boff[NF];
  #pragma unroll
  for (int i = 0; i < MI; ++i) aoff[i] = (wm + i * 16 + l15) * 128;
  #pragma unroll
  for (int j = 0; j < NF; ++j) boff[j] = (wn + j * 16 + l15) * 128;

  f32x4 acc[MI][NF] = {};

  const int nk = K >> 6;
  stage(0, 0);
  for (int t = 0; t < nk; ++t) {
    const int cur = t & 1;
    if (t + 1 < nk) { stage(cur ^ 1, (t + 1) * 64); waitvm<LOADS>(); }
    else waitvm<0>();
    __syncthreads();
    #pragma unroll
    for (int kk = 0; kk < 2; ++kk) {
      const int cb = (kk * 64 + l4 * 16) ^ rswz;
      bf16x8 af[MI], bfr[NF];
      #pragma unroll
      for (int i = 0; i < MI; ++i) af[i] = *(const bf16x8*)(As[cur] + aoff[i] + cb);
      #pragma unroll
      for (int j = 0; j < NF; ++j) bfr[j] = *(const bf16x8*)(Bs[cur] + boff[j] + cb);
      __builtin_amdgcn_s_setprio(1);
      #pragma unroll
      for (int i = 0; i < MI; ++i)
        #pragma unroll
        for (int j = 0; j < NF; ++j)
          acc[i][j] = mfma16(af[i], bfr[j], acc[i][j]);
      __builtin_amdgcn_s_setprio(0);
    }
    __syncthreads();
  }

  const int rowb = m0 + wm + l4 * 4;
  const int colb = n0 + wn + l15;
  #pragma unroll
  for (int i = 0; i < MI; ++i) {
    #pragma unroll
    for (int j = 0; j < NF; ++j) {
      int col = colb + j * 16;
      float bias_v = bias ? bias[col] : 0.f;
      #pragma unroll
      for (int r = 0; r < 4; ++r) {
        int row = rowb + i * 16 + r;
        size_t idx = (size_t)row * N + col;
        float v = acc[i][j][r] + bias_v;
        if (EMODE == 0) {
          if (Cb) { Cf[idx] = v; Cb[idx] = f2bs(v); }
          else __builtin_nontemporal_store(v, &Cf[idx]);
        } else if (EMODE == 1) {
          Cf[idx] += v;
        } else if (EMODE == 2) {
          Cb[idx] = f2bs(fmaxf(v, 0.f));
        } else if (EMODE == 3) {
          float g = 1.f / (1.f + __expf(-v));
          float aggv = ((row & (S_ - 1)) == 0) ? 0.f : bs2f(Agg[idx - N]);
          float tn = Cf[idx] + g * aggv;
          Cf[idx] = tn; Cb[idx] = f2bs(tn);
        } else if (EMODE == 5) {
          float g = 1.f / (1.f + __expf(-v));
          float aggv = ((row & (S_ - 1)) == 0) ? 0.f : bs2f(Agg[idx - N]);
          Hf[idx] += Cf[idx] + g * aggv;
        } else {   // 4: QKV packed bf16; q cols scaled into exp2 domain
          float sc = (col < D_) ? 0.180336880f : 1.f;   // 0.125 * log2(e)
          Cb[idx] = f2bs(v * sc);
        }
      }
    }
  }
}

// ========== 128x128 head GEMM: XCD swizzle, counted vmcnt, COALESCED epilogue ====
__global__ __launch_bounds__(256) void gemm2_k(
    const short* __restrict__ A, const short* __restrict__ Wt,
    float* __restrict__ Cf, int M, int N, int K)
{
  __shared__ __align__(16) char smem[65536];   // As[2][16K] | Bs[2][16K]; reused as Lf
  char* Asb = smem;
  char* Bsb = smem + 32768;
  const int tid = threadIdx.x;
  const int lane = tid & 63, w = tid >> 6;
  // XCD-bijective swizzle (nwg % 8 == 0)
  const int nwg = gridDim.x * gridDim.y;
  const int bid = blockIdx.x + blockIdx.y * gridDim.x;
  const int swz = (bid & 7) * (nwg >> 3) + (bid >> 3);
  const int m0 = (swz % gridDim.x) * 128, n0 = (swz / gridDim.x) * 128;
  const int l15 = lane & 15, l4 = lane >> 4;
  const int wm = (w >> 1) * 64, wn = (w & 1) * 64;

  const int lrow_b = tid >> 3;
  const int kel0 = (tid & 7) * 8;
  const short* agp[4];
  const short* bgp[4];
  #pragma unroll
  for (int r = 0; r < 4; ++r) {
    int lrow = r * 32 + lrow_b;
    int kel = kel0 ^ ((lrow & 7) << 3);
    agp[r] = A + (size_t)(m0 + lrow) * K + kel;
    bgp[r] = Wt + (size_t)(n0 + lrow) * K + kel;
  }
  auto stage = [&](int buf, int k0) {
    #pragma unroll
    for (int r = 0; r < 4; ++r) gload16(agp[r] + k0, Asb + buf * 16384 + r * 4096 + w * 1024);
    #pragma unroll
    for (int r = 0; r < 4; ++r) gload16(bgp[r] + k0, Bsb + buf * 16384 + r * 4096 + w * 1024);
  };

  const int rswz = (l15 & 7) << 4;
  int aoff[4], boff[4];
  #pragma unroll
  for (int i = 0; i < 4; ++i) aoff[i] = (wm + i * 16 + l15) * 128;
  #pragma unroll
  for (int j = 0; j < 4; ++j) boff[j] = (wn + j * 16 + l15) * 128;

  f32x4 acc[4][4] = {};
  const int nk = K >> 6;
  stage(0, 0);
  for (int t = 0; t < nk; ++t) {
    const int cur = t & 1;
    if (t + 1 < nk) { stage(cur ^ 1, (t + 1) * 64); waitvm<8>(); }
    else waitvm<0>();
    __syncthreads();
    #pragma unroll
    for (int kk = 0; kk < 2; ++kk) {
      const int cb = (kk * 64 + l4 * 16) ^ rswz;
      bf16x8 af[4], bfr[4];
      #pragma unroll
      for (int i = 0; i < 4; ++i)
        af[i] = *(const bf16x8*)(Asb + cur * 16384 + aoff[i] + cb);
      #pragma unroll
      for (int j = 0; j < 4; ++j)
        bfr[j] = *(const bf16x8*)(Bsb + cur * 16384 + boff[j] + cb);
      __builtin_amdgcn_s_setprio(1);
      #pragma unroll
      for (int i = 0; i < 4; ++i)
        #pragma unroll
        for (int j = 0; j < 4; ++j)
          acc[i][j] = mfma16(af[i], bfr[j], acc[i][j]);
      __builtin_amdgcn_s_setprio(0);
    }
    __syncthreads();   // last iter: all LDS reads done block-wide after this
  }

  // ---- coalesced epilogue: acc -> swizzled LDS (fp32) -> dwordx4 stores ----
  float* Lf = (float*)smem;        // 128x128 fp32 = 64 KB
  #pragma unroll
  for (int i = 0; i < 4; ++i)
    #pragma unroll
    for (int j = 0; j < 4; ++j)
      #pragma unroll
      for (int r = 0; r < 4; ++r) {
        int row = wm + i * 16 + l4 * 4 + r;
        int c = wn + j * 16 + l15;
        int cs = c ^ ((((row & 7) ^ ((c >> 5) & 3))) << 2);
        Lf[row * 128 + cs] = acc[i][j][r];
      }
  __syncthreads();
  #pragma unroll
  for (int s = 0; s < 16; ++s) {
    int row = (tid >> 5) + s * 8;
    int cb = (tid & 31) * 4;
    int cs = cb ^ ((((row & 7) ^ ((cb >> 5) & 3))) << 2);
    f32x4 v = *(const f32x4*)&Lf[row * 128 + cs];
    __builtin_nontemporal_store(v, (f32x4*)&Cf[(size_t)(m0 + row) * N + n0 + cb]);
  }
}

// ---- flash attention, swapped QK^T (round-7 verified): softmax lane-local;
//      P^T via per-wave LDS; PV with Vt[64][72] XOR-swizzled layout. ----
__global__ __launch_bounds__(256) void fattn_k(const short* __restrict__ Qkv,
    short* __restrict__ avb)
{
  __shared__ short Ks[64][72];        // [key][dh]
  __shared__ short Vt[64][72];        // [dh][key ^ swz]
  __shared__ short Pt[4][16][72];     // per-wave P^T as [q][key]
  const int QS = 3 * D_;
  const int tid = threadIdx.x, lane = tid & 63, w = tid >> 6;
  const int bx = blockIdx.x;
  const int qt = 15 - (bx >> 5);      // heavy tiles first
  const int bh = bx & 31, b = bh >> 3, hh = bh & 7;
  const int l15 = lane & 15, g = lane >> 4;

  const int qrow = qt * 64 + w * 16 + l15;   // this lane's q
  const short* qptr = Qkv + (size_t)(b * S_ + qrow) * QS + hh * DH_;
  bf16x8 qa0 = *(const bf16x8*)(qptr + g * 8);
  bf16x8 qa1 = *(const bf16x8*)(qptr + 32 + g * 8);

  f32x4 o[4] = {};        // o[nt][r] = O[qrow][d = nt*16 + g*4 + r]
  float mx = -1e30f, lsum = 0.f;

  auto gptr = [&](int kt, int i) {
    int c = tid + i * 256;
    int key = c >> 3, d0 = (c & 7) * 8;
    return Qkv + (size_t)(b * S_ + kt * 64 + key) * QS + hh * DH_ + d0;
  };
  uint4 kvA[2], vvA[2], kvB[2], vvB[2];
  auto load_t = [&](int kt, uint4 kv[2], uint4 vv[2]) {
    #pragma unroll
    for (int i = 0; i < 2; ++i) {
      const short* base = gptr(kt, i);
      kv[i] = *(const uint4*)(base + D_);
      vv[i] = *(const uint4*)(base + 2 * D_);
    }
  };
  auto store_t = [&](uint4 kv[2], uint4 vv[2]) {
    #pragma unroll
    for (int i = 0; i < 2; ++i) {
      int c = tid + i * 256;
      int key = c >> 3, d0 = (c & 7) * 8;
      *(uint4*)&Ks[key][d0] = kv[i];
      short vs[8]; *(uint4*)vs = vv[i];
      int a = (c & 7);
      #pragma unroll
      for (int j = 0; j < 8; ++j)
        Vt[d0 + j][key ^ (a << 3)] = vs[j];
    }
  };

  auto compute = [&](int kt) {
    const int key0 = kt * 64;
    f32x4 sc[4] = {};
    __builtin_amdgcn_s_setprio(1);
    #pragma unroll
    for (int f = 0; f < 4; ++f) {
      bf16x8 ka0 = *(const bf16x8*)&Ks[f * 16 + l15][g * 8];
      bf16x8 ka1 = *(const bf16x8*)&Ks[f * 16 + l15][32 + g * 8];
      sc[f] = mfma16(ka0, qa0, sc[f]);
      sc[f] = mfma16(ka1, qa1, sc[f]);
    }
    __builtin_amdgcn_s_setprio(0);

    float s[16];
    #pragma unroll
    for (int f = 0; f < 4; ++f)
      #pragma unroll
      for (int r = 0; r < 4; ++r)
        s[f * 4 + r] = sc[f][r];
    if (kt == qt) {
      #pragma unroll
      for (int f = 0; f < 4; ++f)
        #pragma unroll
        for (int r = 0; r < 4; ++r)
          if (key0 + f * 16 + g * 4 + r > qrow) s[f * 4 + r] = -1e30f;
    }
    float cm = s[0];
    #pragma unroll
    for (int i = 1; i < 16; ++i) cm = fmaxf(cm, s[i]);
    cm = fmaxf(cm, __shfl_xor(cm, 16));
    cm = fmaxf(cm, __shfl_xor(cm, 32));
    float mn = fmaxf(mx, cm);
    float fr = exp2f(mx - mn);
    mx = mn;
    float p[16], ss = 0.f;
    #pragma unroll
    for (int i = 0; i < 16; ++i) { p[i] = exp2f(s[i] - mn); ss += p[i]; }
    ss += __shfl_xor(ss, 16);
    ss += __shfl_xor(ss, 32);
    lsum = lsum * fr + ss;
    #pragma unroll
    for (int nt = 0; nt < 4; ++nt)
      #pragma unroll
      for (int r = 0; r < 4; ++r) o[nt][r] *= fr;

    #pragma unroll
    for (int f = 0; f < 4; ++f) {
      short tmp[4];
      #pragma unroll
      for (int r = 0; r < 4; ++r) tmp[r] = f2bs(p[f * 4 + r]);
      *(uint2*)&Pt[w][l15][f * 16 + g * 4] = *(uint2*)tmp;
    }
    __builtin_amdgcn_sched_barrier(0);
    bf16x8 pb0 = *(const bf16x8*)&Pt[w][l15][g * 8];
    bf16x8 pb1 = *(const bf16x8*)&Pt[w][l15][32 + g * 8];

    __builtin_amdgcn_s_setprio(1);
    #pragma unroll
    for (int nt = 0; nt < 4; ++nt) {
      int dim = nt * 16 + l15;
      int vswz = ((dim >> 3) & 7) << 3;
      bf16x8 va0 = *(const bf16x8*)&Vt[dim][(g * 8) ^ vswz];
      bf16x8 va1 = *(const bf16x8*)&Vt[dim][(32 + g * 8) ^ vswz];
      o[nt] = mfma16(va0, pb0, o[nt]);
      o[nt] = mfma16(va1, pb1, o[nt]);
    }
    __builtin_amdgcn_s_setprio(0);
  };

  const int ntiles = qt + 1;
  load_t(0, kvA, vvA);
  int kt = 0;
  while (true) {
    __syncthreads();
    store_t(kvA, vvA);
    if (kt + 1 < ntiles) load_t(kt + 1, kvB, vvB);
    __syncthreads();
    compute(kt);
    ++kt; if (kt >= ntiles) break;
    __syncthreads();
    store_t(kvB, vvB);
    if (kt + 1 < ntiles) load_t(kt + 1, kvA, vvA);
    __syncthreads();
    compute(kt);
    ++kt; if (kt >= ntiles) break;
  }

  const float inv = 1.f / lsum;
  #pragma unroll
  for (int nt = 0; nt < 4; ++nt) {
    short ov[4];
    #pragma unroll
    for (int r = 0; r < 4; ++r) ov[r] = f2bs(o[nt][r] * inv);
    *(short4b*)(avb + (size_t)(b * S_ + qrow) * D_ + hh * DH_ + nt * 16 + g * 4) =
        *(short4b*)ov;
  }
}

extern "C" void kernel_launch(void* const* d_in, const int* in_sizes, int n_in,
                              void* d_out, int out_size, void* d_ws, size_t ws_size,
                              hipStream_t stream) {
  const int*   ids   = (const int*)d_in[0];
  const float* tok   = (const float*)d_in[1];
  const float* pos   = (const float*)d_in[2];
  const float* Wq    = (const float*)d_in[3];
  const float* bq    = (const float*)d_in[4];
  const float* Wk    = (const float*)d_in[5];
  const float* bk    = (const float*)d_in[6];
  const float* Wv    = (const float*)d_in[7];
  const float* bv    = (const float*)d_in[8];
  const float* Wo    = (const float*)d_in[9];
  const float* bo    = (const float*)d_in[10];
  const float* ln1w  = (const float*)d_in[11];
  const float* ln1b  = (const float*)d_in[12];
  const float* ln2w  = (const float*)d_in[13];
  const float* ln2b  = (const float*)d_in[14];
  const float* Win   = (const float*)d_in[15];
  const float* bin   = (const float*)d_in[16];
  const float* Wedge = (const float*)d_in[17];
  const float* bedge = (const float*)d_in[18];
  const float* Wgate = (const float*)d_in[19];
  const float* bgate = (const float*)d_in[20];
  const float* lnfw  = (const float*)d_in[21];
  const float* lnfb  = (const float*)d_in[22];
  const float* Whead = (const float*)d_in[23];
  float* out = (float*)d_out;

  char* ws = (char*)d_ws;
  size_t off = 0;
  auto alloc = [&](size_t bytes) {
    void* p = ws + off;
    off = (off + bytes + 255) & ~(size_t)255;
    return p;
  };
  short* wqkv   = (short*)alloc((size_t)L_ * 3 * D_ * D_ * 2);
  float* bqkv   = (float*)alloc((size_t)L_ * 3 * D_ * 4);
  short* wto    = (short*)alloc((size_t)L_ * D_ * D_ * 2);
  short* wtin   = (short*)alloc((size_t)L_ * D_ * D_ * 2);
  short* wtgate = (short*)alloc((size_t)L_ * D_ * D_ * 2);
  short* wtedge = (short*)alloc((size_t)L_ * 2 * D_ * D_ * 2);
  short* wthead = (short*)alloc((size_t)V_ * D_ * 2);
  short* zpad   = (short*)alloc(4096);
  float* hbuf   = (float*)alloc((size_t)M_ * D_ * 4);
  short* xb     = (short*)alloc((size_t)M_ * D_ * 2);
  short* qkvb   = (short*)alloc((size_t)M_ * 3 * D_ * 2);
  short* avb    = (short*)alloc((size_t)M_ * D_ * 2);
  float* tbuf   = (float*)alloc((size_t)M_ * D_ * 4);
  short* tbf    = (short*)alloc((size_t)M_ * D_ * 2);
  short* msgb   = (short*)alloc((size_t)M_ * D_ * 2);
  (void)ws_size; (void)in_sizes; (void)n_in; (void)out_size;

  (void)hipMemsetAsync(zpad, 0, 4096, stream);

  dim3 tblk(32, 8);
  transpose_cvt<<<dim3(16, 16, L_), tblk, 0, stream>>>(Wq, wqkv, D_, D_, (size_t)D_*D_, (size_t)3*D_*D_, 0);
  transpose_cvt<<<dim3(16, 16, L_), tblk, 0, stream>>>(Wk, wqkv, D_, D_, (size_t)D_*D_, (size_t)3*D_*D_, D_);
  transpose_cvt<<<dim3(16, 16, L_), tblk, 0, stream>>>(Wv, wqkv, D_, D_, (size_t)D_*D_, (size_t)3*D_*D_, 2*D_);
  transpose_cvt<<<dim3(16, 16, L_), tblk, 0, stream>>>(Wo, wto, D_, D_, (size_t)D_*D_, (size_t)D_*D_, 0);
  transpose_cvt<<<dim3(16, 16, L_), tblk, 0, stream>>>(Win, wtin, D_, D_, (size_t)D_*D_, (size_t)D_*D_, 0);
  transpose_cvt<<<dim3(16, 16, L_), tblk, 0, stream>>>(Wgate, wtgate, D_, D_, (size_t)D_*D_, (size_t)D_*D_, 0);
  transpose_cvt<<<dim3(16, 32, L_), tblk, 0, stream>>>(Wedge, wtedge, 2*D_, D_, (size_t)2*D_*D_, (size_t)2*D_*D_, 0);
  transpose_cvt<<<dim3(V_/32, 16, 1), tblk, 0, stream>>>(Whead, wthead, D_, V_, (size_t)D_*V_, (size_t)D_*V_, 0);
  pack_qkv_bias<<<(L_ * 3 * D_) / 256, 256, 0, stream>>>(bq, bk, bv, bqkv);

  embed_k<<<M_, 256, 0, stream>>>(ids, tok, pos, hbuf);

  dim3 g32(M_ / 32, D_ / 64);         // (128,8) -> 1024 blocks = 4/CU
  dim3 gqkv(M_ / 64, 3 * D_ / 128);   // (64,12) -> 768 blocks (round-10 verified)
  for (int l = 0; l < L_; ++l) {
    size_t wofs = (size_t)l * D_ * D_;
    ln4_k<<<M_ / 4, 256, 0, stream>>>(hbuf, ln1w + l * D_, ln1b + l * D_, xb);
    gemm3_k<0,4,64,128><<<gqkv, 256, 0, stream>>>(xb, wqkv + (size_t)l * 3 * D_ * D_,
        bqkv + (size_t)l * 3 * D_, nullptr, qkvb, nullptr, nullptr, zpad, M_, 3 * D_, D_);
    fattn_k<<<B_ * H_ * (S_ / 64), 256, 0, stream>>>(qkvb, avb);
    gemm3_k<0,1,32,64><<<g32, 256, 0, stream>>>(avb, wto + wofs, bo + l * D_,
        hbuf, nullptr, nullptr, nullptr, zpad, M_, D_, D_);
    ln4_k<<<M_ / 4, 256, 0, stream>>>(hbuf, ln2w + l * D_, ln2b + l * D_, xb);
    gemm3_k<0,0,32,64><<<g32, 256, 0, stream>>>(xb, wtin + wofs, bin + l * D_,
        tbuf, tbf, nullptr, nullptr, zpad, M_, D_, D_);
    // TreeFFN iter 0
    gemm3_k<1,2,32,64><<<g32, 256, 0, stream>>>(tbf, wtedge + (size_t)l * 2 * D_ * D_,
        bedge + l * D_, nullptr, msgb, nullptr, nullptr, zpad, M_, D_, 2 * D_);
    gemm3_k<2,3,32,64><<<g32, 256, 0, stream>>>(msgb, wtgate + wofs, bgate + l * D_,
        tbuf, tbf, msgb, nullptr, zpad, M_, D_, D_);
    // TreeFFN iter 1 + fused residual h += t
    gemm3_k<1,2,32,64><<<g32, 256, 0, stream>>>(tbf, wtedge + (size_t)l * 2 * D_ * D_,
        bedge + l * D_, nullptr, msgb, nullptr, nullptr, zpad, M_, D_, 2 * D_);
    gemm3_k<2,5,32,64><<<g32, 256, 0, stream>>>(msgb, wtgate + wofs, bgate + l * D_,
        tbuf, nullptr, msgb, hbuf, zpad, M_, D_, D_);
  }
  ln4_k<<<M_ / 4, 256, 0, stream>>>(hbuf, lnfw, lnfb, xb);
  gemm2_k<<<dim3(M_ / 128, V_ / 128), 256, 0, stream>>>(xb, wthead, out, M_, V_, D_);
}

// Round 13
// 923.868 us; speedup vs baseline: 1.0445x; 1.0276x over previous
//
#include <hip/hip_runtime.h>
#include <hip/hip_bf16.h>
#include <stdint.h>

#define V_ 32000
#define D_ 512
#define H_ 8
#define L_ 6
#define S_ 1024
#define B_ 4
#define DH_ 64
#define M_ (B_*S_)   // 4096

typedef __attribute__((ext_vector_type(8))) short bf16x8;
typedef __attribute__((ext_vector_type(4))) short short4b;
typedef __attribute__((ext_vector_type(4))) float f32x4;

__device__ __forceinline__ short f2bs(float f) {
  union { float f; uint32_t u; } x; x.f = f;
  uint32_t r = (x.u + 0x7FFFu + ((x.u >> 16) & 1u)) >> 16;
  return (short)r;
}
__device__ __forceinline__ float bs2f(short s) {
  union { uint32_t u; float f; } x; x.u = ((uint32_t)(uint16_t)s) << 16;
  return x.f;
}

__device__ __forceinline__ f32x4 mfma16(bf16x8 a, bf16x8 b, f32x4 c) {
  return __builtin_amdgcn_mfma_f32_16x16x32_bf16(a, b, c, 0, 0, 0);
}

// async global->LDS, 16B per lane; LDS dest = wave-uniform base + lane*16
__device__ __forceinline__ void gload16(const short* g, char* lds) {
  __builtin_amdgcn_global_load_lds(
      (const __attribute__((address_space(1))) uint32_t*)g,
      (__attribute__((address_space(3))) uint32_t*)lds, 16, 0, 0);
}

template<int N> __device__ __forceinline__ void waitvm() {
  if constexpr (N == 0) asm volatile("s_waitcnt vmcnt(0)" ::: "memory");
  else if constexpr (N == 3) asm volatile("s_waitcnt vmcnt(3)" ::: "memory");
  else if constexpr (N == 4) asm volatile("s_waitcnt vmcnt(4)" ::: "memory");
  else if constexpr (N == 6) asm volatile("s_waitcnt vmcnt(6)" ::: "memory");
  else if constexpr (N == 8) asm volatile("s_waitcnt vmcnt(8)" ::: "memory");
}

// ---- transpose + fp32->bf16 convert: out[(orow0+n)*K + k] = in[k*N+n] ----
__global__ __launch_bounds__(256) void transpose_cvt(const float* __restrict__ in,
    short* __restrict__ out, int K, int N, size_t in_slab, size_t out_slab, int orow0) {
  __shared__ float tile[32][33];
  const float* inp = in + (size_t)blockIdx.z * in_slab;
  short* outp = out + (size_t)blockIdx.z * out_slab;
  int kb = blockIdx.y * 32, nb = blockIdx.x * 32;
  int tx = threadIdx.x, ty = threadIdx.y;   // block (32,8)
  for (int r = ty; r < 32; r += 8) {
    int k = kb + r, n = nb + tx;
    tile[r][tx] = (k < K && n < N) ? inp[(size_t)k * N + n] : 0.f;
  }
  __syncthreads();
  for (int r = ty; r < 32; r += 8) {
    int n = nb + r, k = kb + tx;
    if (n < N && k < K) outp[(size_t)(orow0 + n) * K + k] = f2bs(tile[tx][r]);
  }
}

__global__ __launch_bounds__(256) void pack_qkv_bias(const float* __restrict__ bq,
    const float* __restrict__ bk, const float* __restrict__ bv, float* __restrict__ o) {
  int i = blockIdx.x * 256 + threadIdx.x;   // < L_*1536
  int l = i / 1536, c = i - l * 1536;
  float v = (c < 512) ? bq[l * 512 + c] : (c < 1024) ? bk[l * 512 + c - 512]
                                                     : bv[l * 512 + c - 1024];
  o[i] = v;
}

// ---- embedding ----
__global__ __launch_bounds__(256) void embed_k(const int* __restrict__ ids,
    const float* __restrict__ tok, const float* __restrict__ pos, float* __restrict__ h) {
  int bs = blockIdx.x;
  int tid = threadIdx.x;
  int s = bs & (S_ - 1);
  int id = ids[bs];
  float2 te = *(const float2*)(tok + (size_t)id * D_ + tid * 2);
  float2 pe = *(const float2*)(pos + (size_t)s * D_ + tid * 2);
  float2 r; r.x = te.x + pe.x; r.y = te.y + pe.y;
  *(float2*)(h + (size_t)bs * D_ + tid * 2) = r;
}

// ---- LayerNorm, one wave per row, 4 rows/block, no LDS ----
__global__ __launch_bounds__(256) void ln4_k(const float* __restrict__ in,
    const float* __restrict__ w, const float* __restrict__ bb, short* __restrict__ outb) {
  int wv = threadIdx.x >> 6, lane = threadIdx.x & 63;
  int row = blockIdx.x * 4 + wv;
  const float* x = in + (size_t)row * D_ + lane * 8;
  float4 v0 = *(const float4*)x;
  float4 v1 = *(const float4*)(x + 4);
  float s = v0.x + v0.y + v0.z + v0.w + v1.x + v1.y + v1.z + v1.w;
  #pragma unroll
  for (int o = 32; o; o >>= 1) s += __shfl_xor(s, o);
  float mu = s * (1.f / D_);
  float d[8] = {v0.x-mu, v0.y-mu, v0.z-mu, v0.w-mu, v1.x-mu, v1.y-mu, v1.z-mu, v1.w-mu};
  float s2 = 0.f;
  #pragma unroll
  for (int j = 0; j < 8; ++j) s2 += d[j] * d[j];
  #pragma unroll
  for (int o = 32; o; o >>= 1) s2 += __shfl_xor(s2, o);
  float rs = rsqrtf(s2 * (1.f / D_) + 1e-5f);
  float4 w0 = *(const float4*)(w + lane * 8);
  float4 w1 = *(const float4*)(w + lane * 8 + 4);
  float4 b0 = *(const float4*)(bb + lane * 8);
  float4 b1 = *(const float4*)(bb + lane * 8 + 4);
  float wj[8] = {w0.x,w0.y,w0.z,w0.w,w1.x,w1.y,w1.z,w1.w};
  float bj[8] = {b0.x,b0.y,b0.z,b0.w,b1.x,b1.y,b1.z,b1.w};
  short o8[8];
  #pragma unroll
  for (int j = 0; j < 8; ++j) o8[j] = f2bs(d[j] * rs * wj[j] + bj[j]);
  *(uint4*)(outb + (size_t)row * D_ + lane * 8) = *(uint4*)o8;
}

// ========== BMxBN MFMA GEMM, BK=64, dbuf + counted vmcnt (round-10 verified) =====
// EMODE: 0 Cf=acc+b (+Cb if nonnull, else nontemporal); 1 Cf+=; 2 Cb=relu;
//        3 gate-iter0 bf16 carry (Cb = bf16(bs2f(Cb) + sig*agg));
//        5 gate-iter1 bf16 carry (Hf += bs2f(Cb) + sig*agg);
//        4 QKV bf16; 6 Cb=bf16(acc+b) only.
template<int AMODE, int EMODE, int BM, int BN>
__global__ __launch_bounds__(256) void gemm3_k(
    const short* __restrict__ A, const short* __restrict__ Wt,
    const float* __restrict__ bias, float* __restrict__ Cf,
    short* __restrict__ Cb, const short* __restrict__ Agg,
    float* __restrict__ Hf, const short* __restrict__ zpad,
    int M, int N, int K)
{
  constexpr int NF = BN / 32;             // B frags per wave
  constexpr int AR = BM / 32;             // A staging rounds (32 rows each)
  constexpr int BR = BN / 32;             // B staging rounds
  constexpr int MI = BM / 32;             // A frags per wave
  constexpr int LOADS = AR + BR;          // gloads per wave per stage
  __shared__ __align__(16) char As[2][BM * 128];
  __shared__ __align__(16) char Bs[2][BN * 128];
  const int tid = threadIdx.x;
  const int lane = tid & 63, w = tid >> 6;
  const int m0 = blockIdx.x * BM, n0 = blockIdx.y * BN;
  const int l15 = lane & 15, l4 = lane >> 4;
  const int wm = (w >> 1) * (BM / 2), wn = (w & 1) * (BN / 2);

  const int lrow_b = tid >> 3;            // 0..31
  const int kel0 = (tid & 7) * 8;
  const short* agp[AR];
  const short* agpHi[AR];
  #pragma unroll
  for (int r = 0; r < AR; ++r) {
    int lrow = r * 32 + lrow_b;
    int row = m0 + lrow;
    int kel = kel0 ^ ((lrow & 7) << 3);
    if (AMODE == 0) {
      agp[r] = A + (size_t)row * K + kel;
    } else if (AMODE == 1) {
      agp[r]   = A + (size_t)row * D_ + kel;
      agpHi[r] = ((row & (S_ - 1)) == (S_ - 1)) ? zpad + kel
                                                : A + (size_t)(row + 1) * D_ + kel;
    } else {
      agp[r] = ((row & (S_ - 1)) == 0) ? zpad + kel : A + (size_t)(row - 1) * D_ + kel;
    }
  }
  const short* bgp[BR];
  #pragma unroll
  for (int r = 0; r < BR; ++r) {
    int lrow = r * 32 + lrow_b;
    int kel = kel0 ^ ((lrow & 7) << 3);
    bgp[r] = Wt + (size_t)(n0 + lrow) * K + kel;
  }

  auto stage = [&](int buf, int k0) {
    #pragma unroll
    for (int r = 0; r < AR; ++r) {
      const short* gp;
      if (AMODE == 1) gp = (k0 < D_) ? agp[r] + k0 : agpHi[r] + (k0 - D_);
      else gp = agp[r] + k0;
      gload16(gp, As[buf] + r * 4096 + w * 1024);
    }
    #pragma unroll
    for (int r = 0; r < BR; ++r)
      gload16(bgp[r] + k0, Bs[buf] + r * 4096 + w * 1024);
  };

  const int rswz = (l15 & 7) << 4;
  int aoff[MI], boff[NF];
  #pragma unroll
  for (int i = 0; i < MI; ++i) aoff[i] = (wm + i * 16 + l15) * 128;
  #pragma unroll
  for (int j = 0; j < NF; ++j) boff[j] = (wn + j * 16 + l15) * 128;

  f32x4 acc[MI][NF] = {};

  const int nk = K >> 6;
  stage(0, 0);
  for (int t = 0; t < nk; ++t) {
    const int cur = t & 1;
    if (t + 1 < nk) { stage(cur ^ 1, (t + 1) * 64); waitvm<LOADS>(); }
    else waitvm<0>();
    __syncthreads();
    #pragma unroll
    for (int kk = 0; kk < 2; ++kk) {
      const int cb = (kk * 64 + l4 * 16) ^ rswz;
      bf16x8 af[MI], bfr[NF];
      #pragma unroll
      for (int i = 0; i < MI; ++i) af[i] = *(const bf16x8*)(As[cur] + aoff[i] + cb);
      #pragma unroll
      for (int j = 0; j < NF; ++j) bfr[j] = *(const bf16x8*)(Bs[cur] + boff[j] + cb);
      __builtin_amdgcn_s_setprio(1);
      #pragma unroll
      for (int i = 0; i < MI; ++i)
        #pragma unroll
        for (int j = 0; j < NF; ++j)
          acc[i][j] = mfma16(af[i], bfr[j], acc[i][j]);
      __builtin_amdgcn_s_setprio(0);
    }
    __syncthreads();
  }

  const int rowb = m0 + wm + l4 * 4;
  const int colb = n0 + wn + l15;
  #pragma unroll
  for (int i = 0; i < MI; ++i) {
    #pragma unroll
    for (int j = 0; j < NF; ++j) {
      int col = colb + j * 16;
      float bias_v = bias ? bias[col] : 0.f;
      #pragma unroll
      for (int r = 0; r < 4; ++r) {
        int row = rowb + i * 16 + r;
        size_t idx = (size_t)row * N + col;
        float v = acc[i][j][r] + bias_v;
        if (EMODE == 0) {
          if (Cb) { Cf[idx] = v; Cb[idx] = f2bs(v); }
          else __builtin_nontemporal_store(v, &Cf[idx]);
        } else if (EMODE == 1) {
          Cf[idx] += v;
        } else if (EMODE == 2) {
          Cb[idx] = f2bs(fmaxf(v, 0.f));
        } else if (EMODE == 3) {
          float g = 1.f / (1.f + __expf(-v));
          float aggv = ((row & (S_ - 1)) == 0) ? 0.f : bs2f(Agg[idx - N]);
          float tn = bs2f(Cb[idx]) + g * aggv;
          Cb[idx] = f2bs(tn);
        } else if (EMODE == 5) {
          float g = 1.f / (1.f + __expf(-v));
          float aggv = ((row & (S_ - 1)) == 0) ? 0.f : bs2f(Agg[idx - N]);
          Hf[idx] += bs2f(Cb[idx]) + g * aggv;
        } else if (EMODE == 6) {
          Cb[idx] = f2bs(v);
        } else {   // 4: QKV packed bf16; q cols scaled into exp2 domain
          float sc = (col < D_) ? 0.180336880f : 1.f;   // 0.125 * log2(e)
          Cb[idx] = f2bs(v * sc);
        }
      }
    }
  }
}

// ========== 128x128 MFMA GEMM (head), XCD-swizzled, dbuf + counted vmcnt ==========
// (round-10 verified: direct nontemporal scalar stores)
__global__ __launch_bounds__(256) void gemm2_k(
    const short* __restrict__ A, const short* __restrict__ Wt,
    float* __restrict__ Cf, int M, int N, int K)
{
  __shared__ __align__(16) char As[2][128 * 128];
  __shared__ __align__(16) char Bs[2][128 * 128];
  const int tid = threadIdx.x;
  const int lane = tid & 63, w = tid >> 6;
  // XCD-bijective swizzle (nwg % 8 == 0)
  const int nwg = gridDim.x * gridDim.y;
  const int bid = blockIdx.x + blockIdx.y * gridDim.x;
  const int swz = (bid & 7) * (nwg >> 3) + (bid >> 3);
  const int m0 = (swz % gridDim.x) * 128, n0 = (swz / gridDim.x) * 128;
  const int l15 = lane & 15, l4 = lane >> 4;
  const int wm = (w >> 1) * 64, wn = (w & 1) * 64;

  const int lrow_b = tid >> 3;
  const int kel0 = (tid & 7) * 8;
  const short* agp[4];
  const short* bgp[4];
  #pragma unroll
  for (int r = 0; r < 4; ++r) {
    int lrow = r * 32 + lrow_b;
    int kel = kel0 ^ ((lrow & 7) << 3);
    agp[r] = A + (size_t)(m0 + lrow) * K + kel;
    bgp[r] = Wt + (size_t)(n0 + lrow) * K + kel;
  }
  auto stage = [&](int buf, int k0) {
    #pragma unroll
    for (int r = 0; r < 4; ++r) gload16(agp[r] + k0, As[buf] + r * 4096 + w * 1024);
    #pragma unroll
    for (int r = 0; r < 4; ++r) gload16(bgp[r] + k0, Bs[buf] + r * 4096 + w * 1024);
  };

  const int rswz = (l15 & 7) << 4;
  int aoff[4], boff[4];
  #pragma unroll
  for (int i = 0; i < 4; ++i) aoff[i] = (wm + i * 16 + l15) * 128;
  #pragma unroll
  for (int j = 0; j < 4; ++j) boff[j] = (wn + j * 16 + l15) * 128;

  f32x4 acc[4][4] = {};
  const int nk = K >> 6;
  stage(0, 0);
  for (int t = 0; t < nk; ++t) {
    const int cur = t & 1;
    if (t + 1 < nk) { stage(cur ^ 1, (t + 1) * 64); waitvm<8>(); }
    else waitvm<0>();
    __syncthreads();
    #pragma unroll
    for (int kk = 0; kk < 2; ++kk) {
      const int cb = (kk * 64 + l4 * 16) ^ rswz;
      bf16x8 af[4], bfr[4];
      #pragma unroll
      for (int i = 0; i < 4; ++i) af[i] = *(const bf16x8*)(As[cur] + aoff[i] + cb);
      #pragma unroll
      for (int j = 0; j < 4; ++j) bfr[j] = *(const bf16x8*)(Bs[cur] + boff[j] + cb);
      __builtin_amdgcn_s_setprio(1);
      #pragma unroll
      for (int i = 0; i < 4; ++i)
        #pragma unroll
        for (int j = 0; j < 4; ++j)
          acc[i][j] = mfma16(af[i], bfr[j], acc[i][j]);
      __builtin_amdgcn_s_setprio(0);
    }
    __syncthreads();
  }

  const int rowb = m0 + wm + l4 * 4;
  const int colb = n0 + wn + l15;
  #pragma unroll
  for (int i = 0; i < 4; ++i)
    #pragma unroll
    for (int j = 0; j < 4; ++j)
      #pragma unroll
      for (int r = 0; r < 4; ++r) {
        size_t idx = (size_t)(rowb + i * 16 + r) * N + colb + j * 16;
        __builtin_nontemporal_store(acc[i][j][r], &Cf[idx]);
      }
}

// ---- flash attention, swapped QK^T (round-7 verified): softmax lane-local;
//      P^T via per-wave LDS; PV with Vt[64][72] XOR-swizzled layout. ----
__global__ __launch_bounds__(256) void fattn_k(const short* __restrict__ Qkv,
    short* __restrict__ avb)
{
  __shared__ short Ks[64][72];        // [key][dh]
  __shared__ short Vt[64][72];        // [dh][key ^ swz]
  __shared__ short Pt[4][16][72];     // per-wave P^T as [q][key]
  const int QS = 3 * D_;
  const int tid = threadIdx.x, lane = tid & 63, w = tid >> 6;
  const int bx = blockIdx.x;
  const int qt = 15 - (bx >> 5);      // heavy tiles first
  const int bh = bx & 31, b = bh >> 3, hh = bh & 7;
  const int l15 = lane & 15, g = lane >> 4;

  const int qrow = qt * 64 + w * 16 + l15;   // this lane's q
  const short* qptr = Qkv + (size_t)(b * S_ + qrow) * QS + hh * DH_;
  bf16x8 qa0 = *(const bf16x8*)(qptr + g * 8);
  bf16x8 qa1 = *(const bf16x8*)(qptr + 32 + g * 8);

  f32x4 o[4] = {};        // o[nt][r] = O[qrow][d = nt*16 + g*4 + r]
  float mx = -1e30f, lsum = 0.f;

  auto gptr = [&](int kt, int i) {
    int c = tid + i * 256;
    int key = c >> 3, d0 = (c & 7) * 8;
    return Qkv + (size_t)(b * S_ + kt * 64 + key) * QS + hh * DH_ + d0;
  };
  uint4 kvA[2], vvA[2], kvB[2], vvB[2];
  auto load_t = [&](int kt, uint4 kv[2], uint4 vv[2]) {
    #pragma unroll
    for (int i = 0; i < 2; ++i) {
      const short* base = gptr(kt, i);
      kv[i] = *(const uint4*)(base + D_);
      vv[i] = *(const uint4*)(base + 2 * D_);
    }
  };
  auto store_t = [&](uint4 kv[2], uint4 vv[2]) {
    #pragma unroll
    for (int i = 0; i < 2; ++i) {
      int c = tid + i * 256;
      int key = c >> 3, d0 = (c & 7) * 8;
      *(uint4*)&Ks[key][d0] = kv[i];
      short vs[8]; *(uint4*)vs = vv[i];
      int a = (c & 7);
      #pragma unroll
      for (int j = 0; j < 8; ++j)
        Vt[d0 + j][key ^ (a << 3)] = vs[j];
    }
  };

  auto compute = [&](int kt) {
    const int key0 = kt * 64;
    f32x4 sc[4] = {};
    __builtin_amdgcn_s_setprio(1);
    #pragma unroll
    for (int f = 0; f < 4; ++f) {
      bf16x8 ka0 = *(const bf16x8*)&Ks[f * 16 + l15][g * 8];
      bf16x8 ka1 = *(const bf16x8*)&Ks[f * 16 + l15][32 + g * 8];
      sc[f] = mfma16(ka0, qa0, sc[f]);
      sc[f] = mfma16(ka1, qa1, sc[f]);
    }
    __builtin_amdgcn_s_setprio(0);

    float s[16];
    #pragma unroll
    for (int f = 0; f < 4; ++f)
      #pragma unroll
      for (int r = 0; r < 4; ++r)
        s[f * 4 + r] = sc[f][r];
    if (kt == qt) {
      #pragma unroll
      for (int f = 0; f < 4; ++f)
        #pragma unroll
        for (int r = 0; r < 4; ++r)
          if (key0 + f * 16 + g * 4 + r > qrow) s[f * 4 + r] = -1e30f;
    }
    float cm = s[0];
    #pragma unroll
    for (int i = 1; i < 16; ++i) cm = fmaxf(cm, s[i]);
    cm = fmaxf(cm, __shfl_xor(cm, 16));
    cm = fmaxf(cm, __shfl_xor(cm, 32));
    float mn = fmaxf(mx, cm);
    float fr = exp2f(mx - mn);
    mx = mn;
    float p[16], ss = 0.f;
    #pragma unroll
    for (int i = 0; i < 16; ++i) { p[i] = exp2f(s[i] - mn); ss += p[i]; }
    ss += __shfl_xor(ss, 16);
    ss += __shfl_xor(ss, 32);
    lsum = lsum * fr + ss;
    #pragma unroll
    for (int nt = 0; nt < 4; ++nt)
      #pragma unroll
      for (int r = 0; r < 4; ++r) o[nt][r] *= fr;

    #pragma unroll
    for (int f = 0; f < 4; ++f) {
      short tmp[4];
      #pragma unroll
      for (int r = 0; r < 4; ++r) tmp[r] = f2bs(p[f * 4 + r]);
      *(uint2*)&Pt[w][l15][f * 16 + g * 4] = *(uint2*)tmp;
    }
    __builtin_amdgcn_sched_barrier(0);
    bf16x8 pb0 = *(const bf16x8*)&Pt[w][l15][g * 8];
    bf16x8 pb1 = *(const bf16x8*)&Pt[w][l15][32 + g * 8];

    __builtin_amdgcn_s_setprio(1);
    #pragma unroll
    for (int nt = 0; nt < 4; ++nt) {
      int dim = nt * 16 + l15;
      int vswz = ((dim >> 3) & 7) << 3;
      bf16x8 va0 = *(const bf16x8*)&Vt[dim][(g * 8) ^ vswz];
      bf16x8 va1 = *(const bf16x8*)&Vt[dim][(32 + g * 8) ^ vswz];
      o[nt] = mfma16(va0, pb0, o[nt]);
      o[nt] = mfma16(va1, pb1, o[nt]);
    }
    __builtin_amdgcn_s_setprio(0);
  };

  const int ntiles = qt + 1;
  load_t(0, kvA, vvA);
  int kt = 0;
  while (true) {
    __syncthreads();
    store_t(kvA, vvA);
    if (kt + 1 < ntiles) load_t(kt + 1, kvB, vvB);
    __syncthreads();
    compute(kt);
    ++kt; if (kt >= ntiles) break;
    __syncthreads();
    store_t(kvB, vvB);
    if (kt + 1 < ntiles) load_t(kt + 1, kvA, vvA);
    __syncthreads();
    compute(kt);
    ++kt; if (kt >= ntiles) break;
  }

  const float inv = 1.f / lsum;
  #pragma unroll
  for (int nt = 0; nt < 4; ++nt) {
    short ov[4];
    #pragma unroll
    for (int r = 0; r < 4; ++r) ov[r] = f2bs(o[nt][r] * inv);
    *(short4b*)(avb + (size_t)(b * S_ + qrow) * D_ + hh * DH_ + nt * 16 + g * 4) =
        *(short4b*)ov;
  }
}

extern "C" void kernel_launch(void* const* d_in, const int* in_sizes, int n_in,
                              void* d_out, int out_size, void* d_ws, size_t ws_size,
                              hipStream_t stream) {
  const int*   ids   = (const int*)d_in[0];
  const float* tok   = (const float*)d_in[1];
  const float* pos   = (const float*)d_in[2];
  const float* Wq    = (const float*)d_in[3];
  const float* bq    = (const float*)d_in[4];
  const float* Wk    = (const float*)d_in[5];
  const float* bk    = (const float*)d_in[6];
  const float* Wv    = (const float*)d_in[7];
  const float* bv    = (const float*)d_in[8];
  const float* Wo    = (const float*)d_in[9];
  const float* bo    = (const float*)d_in[10];
  const float* ln1w  = (const float*)d_in[11];
  const float* ln1b  = (const float*)d_in[12];
  const float* ln2w  = (const float*)d_in[13];
  const float* ln2b  = (const float*)d_in[14];
  const float* Win   = (const float*)d_in[15];
  const float* bin   = (const float*)d_in[16];
  const float* Wedge = (const float*)d_in[17];
  const float* bedge = (const float*)d_in[18];
  const float* Wgate = (const float*)d_in[19];
  const float* bgate = (const float*)d_in[20];
  const float* lnfw  = (const float*)d_in[21];
  const float* lnfb  = (const float*)d_in[22];
  const float* Whead = (const float*)d_in[23];
  float* out = (float*)d_out;

  char* ws = (char*)d_ws;
  size_t off = 0;
  auto alloc = [&](size_t bytes) {
    void* p = ws + off;
    off = (off + bytes + 255) & ~(size_t)255;
    return p;
  };
  short* wqkv   = (short*)alloc((size_t)L_ * 3 * D_ * D_ * 2);
  float* bqkv   = (float*)alloc((size_t)L_ * 3 * D_ * 4);
  short* wto    = (short*)alloc((size_t)L_ * D_ * D_ * 2);
  short* wtin   = (short*)alloc((size_t)L_ * D_ * D_ * 2);
  short* wtgate = (short*)alloc((size_t)L_ * D_ * D_ * 2);
  short* wtedge = (short*)alloc((size_t)L_ * 2 * D_ * D_ * 2);
  short* wthead = (short*)alloc((size_t)V_ * D_ * 2);
  short* zpad   = (short*)alloc(4096);
  float* hbuf   = (float*)alloc((size_t)M_ * D_ * 4);
  short* xb     = (short*)alloc((size_t)M_ * D_ * 2);
  short* qkvb   = (short*)alloc((size_t)M_ * 3 * D_ * 2);
  short* avb    = (short*)alloc((size_t)M_ * D_ * 2);
  short* tbf    = (short*)alloc((size_t)M_ * D_ * 2);
  short* msgb   = (short*)alloc((size_t)M_ * D_ * 2);
  (void)ws_size; (void)in_sizes; (void)n_in; (void)out_size;

  (void)hipMemsetAsync(zpad, 0, 4096, stream);

  dim3 tblk(32, 8);
  transpose_cvt<<<dim3(16, 16, L_), tblk, 0, stream>>>(Wq, wqkv, D_, D_, (size_t)D_*D_, (size_t)3*D_*D_, 0);
  transpose_cvt<<<dim3(16, 16, L_), tblk, 0, stream>>>(Wk, wqkv, D_, D_, (size_t)D_*D_, (size_t)3*D_*D_, D_);
  transpose_cvt<<<dim3(16, 16, L_), tblk, 0, stream>>>(Wv, wqkv, D_, D_, (size_t)D_*D_, (size_t)3*D_*D_, 2*D_);
  transpose_cvt<<<dim3(16, 16, L_), tblk, 0, stream>>>(Wo, wto, D_, D_, (size_t)D_*D_, (size_t)D_*D_, 0);
  transpose_cvt<<<dim3(16, 16, L_), tblk, 0, stream>>>(Win, wtin, D_, D_, (size_t)D_*D_, (size_t)D_*D_, 0);
  transpose_cvt<<<dim3(16, 16, L_), tblk, 0, stream>>>(Wgate, wtgate, D_, D_, (size_t)D_*D_, (size_t)D_*D_, 0);
  transpose_cvt<<<dim3(16, 32, L_), tblk, 0, stream>>>(Wedge, wtedge, 2*D_, D_, (size_t)2*D_*D_, (size_t)2*D_*D_, 0);
  transpose_cvt<<<dim3(V_/32, 16, 1), tblk, 0, stream>>>(Whead, wthead, D_, V_, (size_t)D_*V_, (size_t)D_*V_, 0);
  pack_qkv_bias<<<(L_ * 3 * D_) / 256, 256, 0, stream>>>(bq, bk, bv, bqkv);

  embed_k<<<M_, 256, 0, stream>>>(ids, tok, pos, hbuf);

  dim3 g32(M_ / 32, D_ / 64);         // (128,8) -> 1024 blocks = 4/CU
  dim3 gqkv(M_ / 64, 3 * D_ / 128);   // (64,12) -> 768 blocks (round-10 verified)
  for (int l = 0; l < L_; ++l) {
    size_t wofs = (size_t)l * D_ * D_;
    ln4_k<<<M_ / 4, 256, 0, stream>>>(hbuf, ln1w + l * D_, ln1b + l * D_, xb);
    gemm3_k<0,4,64,128><<<gqkv, 256, 0, stream>>>(xb, wqkv + (size_t)l * 3 * D_ * D_,
        bqkv + (size_t)l * 3 * D_, nullptr, qkvb, nullptr, nullptr, zpad, M_, 3 * D_, D_);
    fattn_k<<<B_ * H_ * (S_ / 64), 256, 0, stream>>>(qkvb, avb);
    gemm3_k<0,1,32,64><<<g32, 256, 0, stream>>>(avb, wto + wofs, bo + l * D_,
        hbuf, nullptr, nullptr, nullptr, zpad, M_, D_, D_);
    ln4_k<<<M_ / 4, 256, 0, stream>>>(hbuf, ln2w + l * D_, ln2b + l * D_, xb);
    // t (bf16 carry) = x @ Win + b
    gemm3_k<0,6,32,64><<<g32, 256, 0, stream>>>(xb, wtin + wofs, bin + l * D_,
        nullptr, tbf, nullptr, nullptr, zpad, M_, D_, D_);
    // TreeFFN iter 0
    gemm3_k<1,2,32,64><<<g32, 256, 0, stream>>>(tbf, wtedge + (size_t)l * 2 * D_ * D_,
        bedge + l * D_, nullptr, msgb, nullptr, nullptr, zpad, M_, D_, 2 * D_);
    gemm3_k<2,3,32,64><<<g32, 256, 0, stream>>>(msgb, wtgate + wofs, bgate + l * D_,
        nullptr, tbf, msgb, nullptr, zpad, M_, D_, D_);
    // TreeFFN iter 1 + fused residual h += t
    gemm3_k<1,2,32,64><<<g32, 256, 0, stream>>>(tbf, wtedge + (size_t)l * 2 * D_ * D_,
        bedge + l * D_, nullptr, msgb, nullptr, nullptr, zpad, M_, D_, 2 * D_);
    gemm3_k<2,5,32,64><<<g32, 256, 0, stream>>>(msgb, wtgate + wofs, bgate + l * D_,
        nullptr, tbf, msgb, hbuf, zpad, M_, D_, D_);
  }
  ln4_k<<<M_ / 4, 256, 0, stream>>>(hbuf, lnfw, lnfb, xb);
  gemm2_k<<<dim3(M_ / 128, V_ / 128), 256, 0, stream>>>(xb, wthead, out, M_, V_, D_);
}